// Round 1
// baseline (5904.556 us; speedup 1.0000x reference)
//
#include <hip/hip_runtime.h>

typedef unsigned short u16;
typedef short bf16x8 __attribute__((ext_vector_type(8)));
typedef float f32x4 __attribute__((ext_vector_type(4)));

#define Bq 1024
#define Tq 256
#define Dq 128
#define Hq 512
#define GH 2048
#define Zq 64
#define GN 32
#define GM 8
#define MB 128

// workspace layout (bytes)
#define XP_OFF   0ull                      // x packed [T][B][D] bf16  : 67108864 B
#define WP_OFF   (XP_OFF + 67108864ull)    // W/U packed frags 32*81920: 2621440 B
#define HB_OFF   (WP_OFF + 2621440ull)     // h double buffer 2*[B][H] : 2097152 B
#define CT_OFF   (HB_OFF + 2097152ull)     // row barrier counters     : 4096 B

__device__ __forceinline__ u16 f2bf(float f){
  unsigned int u = __builtin_bit_cast(unsigned int, f);
  u += 0x7fffu + ((u >> 16) & 1u);          // RNE; inputs finite
  return (u16)(u >> 16);
}
__device__ __forceinline__ float bf2f(u16 v){
  unsigned int u = ((unsigned int)v) << 16;
  return __builtin_bit_cast(float, u);
}
__device__ __forceinline__ float sigmf_(float x){
  return 1.0f / (1.0f + __expf(-x));
}
__device__ __forceinline__ float softplusf_(float x){
  float r = __logf(1.0f + __expf(x));
  return (x > 20.0f) ? x : r;               // guard overflow: softplus(x)->x
}

// ---- pack x [B,T,D] fp32 -> [T,B,D] bf16 -------------------------------
__global__ __launch_bounds__(256) void pack_x_k(const float4* __restrict__ x,
                                                ushort4* __restrict__ xp){
  int idx = blockIdx.x * 256 + threadIdx.x;          // 8,388,608 float4s
  int t = idx >> 15, rem = idx & 32767, b = rem >> 5, d4 = rem & 31;
  float4 v = x[(size_t)b * 8192 + t * 32 + d4];
  ushort4 o;
  o.x = f2bf(v.x); o.y = f2bf(v.y); o.z = f2bf(v.z); o.w = f2bf(v.w);
  xp[idx] = o;
}

// ---- pack [W;U] into per-block MFMA B-fragment images ------------------
// block j owns h-cols j*16..j*16+15 -> gate cols n*512 + j*16 + (0..15)
// frag layout: lane holds B[k = kcg*32 + (lane>>4)*8 + jj][col = n-tile col]
__global__ __launch_bounds__(256) void pack_w_k(const float* __restrict__ W,
                                                const float* __restrict__ U,
                                                u16* __restrict__ wp){
  int idx = blockIdx.x * 256 + threadIdx.x;          // 163840 threads
  int j = idx / 5120; int rem = idx % 5120;
  int kcg = rem >> 8; int rem2 = rem & 255;
  int n = rem2 >> 6; int lane = rem2 & 63;
  int col  = n * Hq + j * 16 + (lane & 15);
  int krow = kcg * 32 + ((lane >> 4) * 8);
  u16 vals[8];
  #pragma unroll
  for (int jj = 0; jj < 8; ++jj){
    int k = krow + jj;
    float v = (k < Dq) ? W[(size_t)k * GH + col] : U[(size_t)(k - Dq) * GH + col];
    vals[jj] = f2bf(v);
  }
  ushort4* dst = (ushort4*)(wp + (size_t)j * 40960 + ((size_t)(kcg * 4 + n) * 64 + lane) * 8);
  dst[0] = make_ushort4(vals[0], vals[1], vals[2], vals[3]);
  dst[1] = make_ushort4(vals[4], vals[5], vals[6], vals[7]);
}

// ---- persistent LSTM recurrence ---------------------------------------
// grid 8x32: block (i,j): batch rows i*128..+128, h-cols j*16..+16.
// Row i's 32 blocks sync via a row barrier; rows independent.
__global__ __launch_bounds__(256, 1) void lstm_k(
    const u16* __restrict__ xp, const u16* __restrict__ wp,
    const float* __restrict__ bias, u16* __restrict__ hb,
    unsigned int* __restrict__ ctr)
{
  __shared__ u16 WL[32768];                 // U-part B-frags, 64 KB
  const int bx = blockIdx.x;
  const int i = bx >> 5, j = bx & 31;
  const int tid = threadIdx.x;
  const int lane = tid & 63, wv = tid >> 6;
  const int l15 = lane & 15, quad = lane >> 4;
  const int koff = quad * 8;

  // x-part weights (K=0..127) -> registers: wx[kc][n]
  const u16* wj = wp + (size_t)j * 40960;
  bf16x8 wx[4][4];
  #pragma unroll
  for (int kc = 0; kc < 4; ++kc)
    #pragma unroll
    for (int n = 0; n < 4; ++n)
      wx[kc][n] = *(const bf16x8*)(wj + ((kc * 4 + n) * 64 + lane) * 8);

  // U-part weights (K=128..639) -> LDS (tiles kcg 4..19 -> kc 0..15)
  {
    const uint4* src = (const uint4*)(wj + 8192);
    uint4* dst = (uint4*)WL;
    #pragma unroll
    for (int q = 0; q < 16; ++q) dst[tid + q * 256] = src[tid + q * 256];
  }
  __syncthreads();

  const int hc = j * 16 + l15;
  const float bi  = bias[hc];
  const float bf_ = bias[Hq + hc];
  const float bg  = bias[2 * Hq + hc];
  const float bo  = bias[3 * Hq + hc];
  const int row0 = i * MB + wv * 32 + l15;  // strip0 A-row; strip1 = +16
  float cst[2][4] = {{0.f,0.f,0.f,0.f},{0.f,0.f,0.f,0.f}};
  unsigned int* myctr = ctr + i * 32;

  for (int t = 0; t < Tq; ++t){
    f32x4 acc[2][4];
    #pragma unroll
    for (int s = 0; s < 2; ++s)
      #pragma unroll
      for (int n = 0; n < 4; ++n)
        acc[s][n] = (f32x4){0.f, 0.f, 0.f, 0.f};

    // ---- K part 1: x_t (kc 0..3), B from registers ----
    const u16* xt = xp + (size_t)t * (Bq * Dq);
    bf16x8 ax[4][2];
    #pragma unroll
    for (int kc = 0; kc < 4; ++kc){
      ax[kc][0] = *(const bf16x8*)(xt + (size_t)row0 * Dq + kc * 32 + koff);
      ax[kc][1] = *(const bf16x8*)(xt + (size_t)(row0 + 16) * Dq + kc * 32 + koff);
    }
    #pragma unroll
    for (int kc = 0; kc < 4; ++kc)
      #pragma unroll
      for (int n = 0; n < 4; ++n){
        acc[0][n] = __builtin_amdgcn_mfma_f32_16x16x32_bf16(ax[kc][0], wx[kc][n], acc[0][n], 0, 0, 0);
        acc[1][n] = __builtin_amdgcn_mfma_f32_16x16x32_bf16(ax[kc][1], wx[kc][n], acc[1][n], 0, 0, 0);
      }

    // ---- K part 2: h_t (kc 0..15), B from LDS ----
    if (t > 0){
      const u16* hcur = hb + (size_t)(t & 1) * (Bq * Hq);
      bf16x8 ah[16][2];
      #pragma unroll
      for (int kc = 0; kc < 16; ++kc){
        ah[kc][0] = *(const bf16x8*)(hcur + (size_t)row0 * Hq + kc * 32 + koff);
        ah[kc][1] = *(const bf16x8*)(hcur + (size_t)(row0 + 16) * Hq + kc * 32 + koff);
      }
      #pragma unroll
      for (int kc = 0; kc < 16; ++kc){
        #pragma unroll
        for (int n = 0; n < 4; ++n){
          bf16x8 bw = *(const bf16x8*)(WL + ((kc * 4 + n) * 64 + lane) * 8);
          acc[0][n] = __builtin_amdgcn_mfma_f32_16x16x32_bf16(ah[kc][0], bw, acc[0][n], 0, 0, 0);
          acc[1][n] = __builtin_amdgcn_mfma_f32_16x16x32_bf16(ah[kc][1], bw, acc[1][n], 0, 0, 0);
        }
      }
    }

    // ---- gate epilogue; c stays in registers; write h_{t+1} bf16 ----
    // C-layout: col = lane&15 (= h-col), row = quad*4 + reg  [m89/m91]
    u16* hn = hb + (size_t)((t + 1) & 1) * (Bq * Hq);
    #pragma unroll
    for (int s = 0; s < 2; ++s){
      #pragma unroll
      for (int r = 0; r < 4; ++r){
        float gi = acc[s][0][r] + bi;
        float gf = acc[s][1][r] + bf_;
        float gg = acc[s][2][r] + bg;
        float go = acc[s][3][r] + bo;
        float iv = sigmf_(gi), fv = sigmf_(gf);
        float gv = softplusf_(gg), ov = sigmf_(go);
        float cn = fv * cst[s][r] + iv * gv;
        cst[s][r] = cn;
        float hv = ov * softplusf_(cn);
        int row = (row0 - l15) + s * 16 + quad * 4 + r;
        hn[(size_t)row * Hq + hc] = f2bf(hv);
      }
    }

    // ---- row barrier (32 blocks), release/acquire at agent scope ----
    __syncthreads();                        // drains vmcnt: h stores in L2
    if (tid == 0){
      __builtin_amdgcn_fence(__ATOMIC_RELEASE, "agent");   // wb L2 -> coherence pt
      __hip_atomic_fetch_add(myctr, 1u, __ATOMIC_RELAXED, __HIP_MEMORY_SCOPE_AGENT);
      unsigned int target = (unsigned int)(GN * (t + 1));
      while (__hip_atomic_load(myctr, __ATOMIC_RELAXED, __HIP_MEMORY_SCOPE_AGENT) < target){
        __builtin_amdgcn_s_sleep(2);
      }
    }
    __syncthreads();
    __builtin_amdgcn_fence(__ATOMIC_ACQUIRE, "agent");     // inv L1/L2 before h reads
  }
}

// ---- final projection: mu, logvar, z ----------------------------------
__global__ __launch_bounds__(64) void proj_k(const u16* __restrict__ h0,
    const float* __restrict__ Wm, const float* __restrict__ bm,
    const float* __restrict__ Wv, const float* __restrict__ bv,
    const float* __restrict__ eps, float* __restrict__ out)
{
  __shared__ float hs[Hq];
  int b = blockIdx.x, lane = threadIdx.x;
  const u16* hr = h0 + (size_t)b * Hq;
  #pragma unroll
  for (int q = 0; q < 8; ++q) hs[lane * 8 + q] = bf2f(hr[lane * 8 + q]);
  __syncthreads();
  float am = 0.f, av = 0.f;
  #pragma unroll 8
  for (int k = 0; k < Hq; ++k){
    float h = hs[k];
    am = fmaf(h, Wm[(size_t)k * Zq + lane], am);
    av = fmaf(h, Wv[(size_t)k * Zq + lane], av);
  }
  float mu = am + bm[lane];
  float lv = av + bv[lane];
  float z  = mu + eps[(size_t)b * Zq + lane] * expf(0.5f * lv);
  size_t o = (size_t)b * Zq + lane;
  out[o]           = mu;
  out[65536 + o]   = lv;
  out[131072 + o]  = z;
}

extern "C" void kernel_launch(void* const* d_in, const int* in_sizes, int n_in,
                              void* d_out, int out_size, void* d_ws, size_t ws_size,
                              hipStream_t stream)
{
  const float* x   = (const float*)d_in[0];
  const float* eps = (const float*)d_in[1];
  const float* W   = (const float*)d_in[2];
  const float* U   = (const float*)d_in[3];
  const float* bb  = (const float*)d_in[4];
  const float* Wm  = (const float*)d_in[5];
  const float* bm  = (const float*)d_in[6];
  const float* Wv  = (const float*)d_in[7];
  const float* bv  = (const float*)d_in[8];

  char* ws = (char*)d_ws;
  u16* xp = (u16*)(ws + XP_OFF);
  u16* wp = (u16*)(ws + WP_OFF);
  u16* hb = (u16*)(ws + HB_OFF);
  unsigned int* ctr = (unsigned int*)(ws + CT_OFF);

  hipMemsetAsync(ctr, 0, 4096, stream);
  pack_x_k<<<32768, 256, 0, stream>>>((const float4*)x, (ushort4*)xp);
  pack_w_k<<<640, 256, 0, stream>>>(W, U, wp);
  lstm_k<<<GM * GN, 256, 0, stream>>>(xp, wp, bb, hb, ctr);
  // after 256 steps, h_last sits in parity (256 & 1) == 0
  proj_k<<<Bq, 64, 0, stream>>>(hb, Wm, bm, Wv, bv, eps, (float*)d_out);
}

// Round 2
// 3152.514 us; speedup vs baseline: 1.8730x; 1.8730x over previous
//
#include <hip/hip_runtime.h>

typedef unsigned short u16;
typedef unsigned long long u64;
typedef short bf16x8 __attribute__((ext_vector_type(8)));
typedef float f32x4 __attribute__((ext_vector_type(4)));

#define Bq 1024
#define Tq 256
#define Dq 128
#define Hq 512
#define GH 2048
#define Zq 64
#define GN 32
#define GM 8
#define MB 128

// workspace layout (bytes)
#define XP_OFF   0ull                      // x packed [T][B][D] bf16  : 67108864 B
#define WP_OFF   (XP_OFF + 67108864ull)    // W/U packed frags 32*81920: 2621440 B
#define HB_OFF   (WP_OFF + 2621440ull)     // h double buffer 2*[B][H] : 2097152 B
#define CT_OFF   (HB_OFF + 2097152ull)     // row barrier counters     : 4096 B

__device__ __forceinline__ u16 f2bf(float f){
  unsigned int u = __builtin_bit_cast(unsigned int, f);
  u += 0x7fffu + ((u >> 16) & 1u);          // RNE; inputs finite
  return (u16)(u >> 16);
}
__device__ __forceinline__ float bf2f(u16 v){
  unsigned int u = ((unsigned int)v) << 16;
  return __builtin_bit_cast(float, u);
}
__device__ __forceinline__ float sigmf_(float x){
  return 1.0f / (1.0f + __expf(-x));
}
__device__ __forceinline__ float softplusf_(float x){
  float r = __logf(1.0f + __expf(x));
  return (x > 20.0f) ? x : r;               // guard overflow: softplus(x)->x
}

// coherent (cross-XCD) accesses: relaxed agent atomics -> global_*  sc1,
// which bypass the non-coherent per-XCD L2. No cache-wide fences needed.
__device__ __forceinline__ void st_h(u16* p, u16 v){
  __hip_atomic_store(p, v, __ATOMIC_RELAXED, __HIP_MEMORY_SCOPE_AGENT);
}
__device__ __forceinline__ bf16x8 ld_h16(const u16* p){
  union { u64 q[2]; bf16x8 v; } u;
  const u64* q = (const u64*)p;
  u.q[0] = __hip_atomic_load(q,     __ATOMIC_RELAXED, __HIP_MEMORY_SCOPE_AGENT);
  u.q[1] = __hip_atomic_load(q + 1, __ATOMIC_RELAXED, __HIP_MEMORY_SCOPE_AGENT);
  return u.v;
}

// ---- pack x [B,T,D] fp32 -> [T,B,D] bf16 -------------------------------
__global__ __launch_bounds__(256) void pack_x_k(const float4* __restrict__ x,
                                                ushort4* __restrict__ xp){
  int idx = blockIdx.x * 256 + threadIdx.x;          // 8,388,608 float4s
  int t = idx >> 15, rem = idx & 32767, b = rem >> 5, d4 = rem & 31;
  float4 v = x[(size_t)b * 8192 + t * 32 + d4];
  ushort4 o;
  o.x = f2bf(v.x); o.y = f2bf(v.y); o.z = f2bf(v.z); o.w = f2bf(v.w);
  xp[idx] = o;
}

// ---- pack [W;U] into per-block MFMA B-fragment images ------------------
__global__ __launch_bounds__(256) void pack_w_k(const float* __restrict__ W,
                                                const float* __restrict__ U,
                                                u16* __restrict__ wp){
  int idx = blockIdx.x * 256 + threadIdx.x;          // 163840 threads
  int j = idx / 5120; int rem = idx % 5120;
  int kcg = rem >> 8; int rem2 = rem & 255;
  int n = rem2 >> 6; int lane = rem2 & 63;
  int col  = n * Hq + j * 16 + (lane & 15);
  int krow = kcg * 32 + ((lane >> 4) * 8);
  u16 vals[8];
  #pragma unroll
  for (int jj = 0; jj < 8; ++jj){
    int k = krow + jj;
    float v = (k < Dq) ? W[(size_t)k * GH + col] : U[(size_t)(k - Dq) * GH + col];
    vals[jj] = f2bf(v);
  }
  ushort4* dst = (ushort4*)(wp + (size_t)j * 40960 + ((size_t)(kcg * 4 + n) * 64 + lane) * 8);
  dst[0] = make_ushort4(vals[0], vals[1], vals[2], vals[3]);
  dst[1] = make_ushort4(vals[4], vals[5], vals[6], vals[7]);
}

// ---- persistent LSTM recurrence ---------------------------------------
// grid 8x32: block (i,j): batch rows i*128..+128, h-cols j*16..+16.
// Row i's 32 blocks sync via a row barrier; rows independent.
// h exchange goes through L3 (sc1 bypass); x/weights stay L2/LDS-cached.
__global__ __launch_bounds__(256, 1) void lstm_k(
    const u16* __restrict__ xp, const u16* __restrict__ wp,
    const float* __restrict__ bias, u16* __restrict__ hb,
    unsigned int* __restrict__ ctr)
{
  __shared__ u16 WL[32768];                 // U-part B-frags, 64 KB
  const int bx = blockIdx.x;
  const int i = bx >> 5, j = bx & 31;
  const int tid = threadIdx.x;
  const int lane = tid & 63, wv = tid >> 6;
  const int l15 = lane & 15, quad = lane >> 4;
  const int koff = quad * 8;

  // x-part weights (K=0..127) -> registers: wx[kc][n]
  const u16* wj = wp + (size_t)j * 40960;
  bf16x8 wx[4][4];
  #pragma unroll
  for (int kc = 0; kc < 4; ++kc)
    #pragma unroll
    for (int n = 0; n < 4; ++n)
      wx[kc][n] = *(const bf16x8*)(wj + ((kc * 4 + n) * 64 + lane) * 8);

  // U-part weights (K=128..639) -> LDS
  {
    const uint4* src = (const uint4*)(wj + 8192);
    uint4* dst = (uint4*)WL;
    #pragma unroll
    for (int q = 0; q < 16; ++q) dst[tid + q * 256] = src[tid + q * 256];
  }
  __syncthreads();

  const int hc = j * 16 + l15;
  const float bi  = bias[hc];
  const float bf_ = bias[Hq + hc];
  const float bg  = bias[2 * Hq + hc];
  const float bo  = bias[3 * Hq + hc];
  const int row0 = i * MB + wv * 32 + l15;  // strip0 A-row; strip1 = +16
  float cst[2][4] = {{0.f,0.f,0.f,0.f},{0.f,0.f,0.f,0.f}};
  unsigned int* myctr = ctr + i * 32;

  for (int t = 0; t < Tq; ++t){
    f32x4 acc[2][4];
    #pragma unroll
    for (int s = 0; s < 2; ++s)
      #pragma unroll
      for (int n = 0; n < 4; ++n)
        acc[s][n] = (f32x4){0.f, 0.f, 0.f, 0.f};

    // ---- K part 1: x_t (kc 0..3), B from registers, normal cached loads ----
    const u16* xt = xp + (size_t)t * (Bq * Dq);
    bf16x8 ax[4][2];
    #pragma unroll
    for (int kc = 0; kc < 4; ++kc){
      ax[kc][0] = *(const bf16x8*)(xt + (size_t)row0 * Dq + kc * 32 + koff);
      ax[kc][1] = *(const bf16x8*)(xt + (size_t)(row0 + 16) * Dq + kc * 32 + koff);
    }
    #pragma unroll
    for (int kc = 0; kc < 4; ++kc)
      #pragma unroll
      for (int n = 0; n < 4; ++n){
        acc[0][n] = __builtin_amdgcn_mfma_f32_16x16x32_bf16(ax[kc][0], wx[kc][n], acc[0][n], 0, 0, 0);
        acc[1][n] = __builtin_amdgcn_mfma_f32_16x16x32_bf16(ax[kc][1], wx[kc][n], acc[1][n], 0, 0, 0);
      }

    // ---- K part 2: h_t (kc 0..15), A via L3-coherent loads, B from LDS ----
    if (t > 0){
      const u16* hcur = hb + (size_t)(t & 1) * (Bq * Hq);
      bf16x8 ah[16][2];
      #pragma unroll
      for (int kc = 0; kc < 16; ++kc){
        ah[kc][0] = ld_h16(hcur + (size_t)row0 * Hq + kc * 32 + koff);
        ah[kc][1] = ld_h16(hcur + (size_t)(row0 + 16) * Hq + kc * 32 + koff);
      }
      #pragma unroll
      for (int kc = 0; kc < 16; ++kc){
        #pragma unroll
        for (int n = 0; n < 4; ++n){
          bf16x8 bw = *(const bf16x8*)(WL + ((kc * 4 + n) * 64 + lane) * 8);
          acc[0][n] = __builtin_amdgcn_mfma_f32_16x16x32_bf16(ah[kc][0], bw, acc[0][n], 0, 0, 0);
          acc[1][n] = __builtin_amdgcn_mfma_f32_16x16x32_bf16(ah[kc][1], bw, acc[1][n], 0, 0, 0);
        }
      }
    }

    // ---- gate epilogue; c stays in registers; write h_{t+1} (L3-coherent) ----
    // C-layout: col = lane&15 (= h-col), row = quad*4 + reg  [m89/m91]
    u16* hn = hb + (size_t)((t + 1) & 1) * (Bq * Hq);
    #pragma unroll
    for (int s = 0; s < 2; ++s){
      #pragma unroll
      for (int r = 0; r < 4; ++r){
        float gi = acc[s][0][r] + bi;
        float gf = acc[s][1][r] + bf_;
        float gg = acc[s][2][r] + bg;
        float go = acc[s][3][r] + bo;
        float iv = sigmf_(gi), fv = sigmf_(gf);
        float gv = softplusf_(gg), ov = sigmf_(go);
        float cn = fv * cst[s][r] + iv * gv;
        cst[s][r] = cn;
        float hv = ov * softplusf_(cn);
        int row = (row0 - l15) + s * 16 + quad * 4 + r;
        st_h(hn + (size_t)row * Hq + hc, f2bf(hv));
      }
    }

    // ---- row barrier (32 blocks). Compiler drains vmcnt(0) at s_barrier,
    // so h stores reached the coherence point before the arrive. ----
    __syncthreads();
    if (tid == 0){
      __hip_atomic_fetch_add(myctr, 1u, __ATOMIC_RELAXED, __HIP_MEMORY_SCOPE_AGENT);
      unsigned int target = (unsigned int)(GN * (t + 1));
      while (__hip_atomic_load(myctr, __ATOMIC_RELAXED, __HIP_MEMORY_SCOPE_AGENT) < target){
        __builtin_amdgcn_s_sleep(1);
      }
    }
    __syncthreads();
  }
}

// ---- final projection: mu, logvar, z ----------------------------------
__global__ __launch_bounds__(64) void proj_k(const u16* __restrict__ h0,
    const float* __restrict__ Wm, const float* __restrict__ bm,
    const float* __restrict__ Wv, const float* __restrict__ bv,
    const float* __restrict__ eps, float* __restrict__ out)
{
  __shared__ float hs[Hq];
  int b = blockIdx.x, lane = threadIdx.x;
  const u16* hr = h0 + (size_t)b * Hq;
  #pragma unroll
  for (int q = 0; q < 8; ++q) hs[lane * 8 + q] = bf2f(hr[lane * 8 + q]);
  __syncthreads();
  float am = 0.f, av = 0.f;
  #pragma unroll 8
  for (int k = 0; k < Hq; ++k){
    float h = hs[k];
    am = fmaf(h, Wm[(size_t)k * Zq + lane], am);
    av = fmaf(h, Wv[(size_t)k * Zq + lane], av);
  }
  float mu = am + bm[lane];
  float lv = av + bv[lane];
  float z  = mu + eps[(size_t)b * Zq + lane] * expf(0.5f * lv);
  size_t o = (size_t)b * Zq + lane;
  out[o]           = mu;
  out[65536 + o]   = lv;
  out[131072 + o]  = z;
}

extern "C" void kernel_launch(void* const* d_in, const int* in_sizes, int n_in,
                              void* d_out, int out_size, void* d_ws, size_t ws_size,
                              hipStream_t stream)
{
  const float* x   = (const float*)d_in[0];
  const float* eps = (const float*)d_in[1];
  const float* W   = (const float*)d_in[2];
  const float* U   = (const float*)d_in[3];
  const float* bb  = (const float*)d_in[4];
  const float* Wm  = (const float*)d_in[5];
  const float* bm  = (const float*)d_in[6];
  const float* Wv  = (const float*)d_in[7];
  const float* bv  = (const float*)d_in[8];

  char* ws = (char*)d_ws;
  u16* xp = (u16*)(ws + XP_OFF);
  u16* wp = (u16*)(ws + WP_OFF);
  u16* hb = (u16*)(ws + HB_OFF);
  unsigned int* ctr = (unsigned int*)(ws + CT_OFF);

  hipMemsetAsync(ctr, 0, 4096, stream);
  pack_x_k<<<32768, 256, 0, stream>>>((const float4*)x, (ushort4*)xp);
  pack_w_k<<<640, 256, 0, stream>>>(W, U, wp);
  lstm_k<<<GM * GN, 256, 0, stream>>>(xp, wp, bb, hb, ctr);
  // after 256 steps, h_last sits in parity (256 & 1) == 0
  proj_k<<<Bq, 64, 0, stream>>>(hb, Wm, bm, Wv, bv, eps, (float*)d_out);
}